// Round 9
// baseline (90152.197 us; speedup 1.0000x reference)
//
#include <hip/hip_runtime.h>
#include <hip/hip_bf16.h>

typedef unsigned short u16;

// ---------------- workspace layout (bytes) ----------------
#define WS_FWD    0            // 384 int
#define WS_SCALE  4096         // 384 f32
#define WS_OFFS   6144         // 384 f32
#define WS_Y2     2097152      // y2' bf16 (b,h,w,c192): 12,582,912 B
#define WS_A      16777216     // a1/a2 bf16 (b,h,w,n384): 25,165,824 B -> ends 41,943,040

static __device__ __forceinline__ u16 f2bf(float f) {
    __hip_bfloat16 h = __float2bfloat16(f);
    return *reinterpret_cast<u16*>(&h);
}
static __device__ __forceinline__ float bf2f(u16 u) {
    __hip_bfloat16 h = *reinterpret_cast<__hip_bfloat16*>(&u);
    return __bfloat162float(h);
}

// ---------------- prep: perm index + scale/offset ----------------
// pw[o,c] = 1 iff c == perm[o]; einsum('bchw,oc->bohw') => out[b,o] = z[b, perm[o]]
__global__ __launch_bounds__(256)
void k_prep0(const float* __restrict__ pw, const float* __restrict__ an,
             const float* __restrict__ ao, int* __restrict__ fwd,
             float* __restrict__ scale, float* __restrict__ offs)
{
    int o = blockIdx.x * 256 + threadIdx.x;
    if (o >= 384) return;
    int f = 0;
    for (int c = 0; c < 384; ++c)
        if (pw[(size_t)o * 384 + c] > 0.5f) f = c;
    fwd[o]   = f;
    scale[o] = 0.2f * log1pf(expf(0.5f * an[o]));
    offs[o]  = ao[o];
}

// ---------------- naive conv_hi: a1[b,oh,ow,n] = conv(x1, w_hi, stride2, pad1) ----------------
// x: (32,96,64,64) f32, channels 0..47 = x1. w_hi: (384,48,3,3) f32. JAX conv = cross-correlation.
__global__ __launch_bounds__(256)
void n_conv_hi(const float* __restrict__ x, const float* __restrict__ w_hi,
               const float* __restrict__ b_hi, u16* __restrict__ a)
{
    int gid = blockIdx.x * 256 + threadIdx.x;        // 12,582,912 exact
    int n = gid % 384;
    int pix = gid / 384;                             // b*1024 + oh*32 + ow
    int b = pix >> 10, oh = (pix >> 5) & 31, ow = pix & 31;
    float s = b_hi[n];
    for (int cin = 0; cin < 48; ++cin) {
        const float* xc = x + ((size_t)b * 96 + cin) * 4096;
        const float* wc = w_hi + ((size_t)n * 48 + cin) * 9;
        for (int ky = 0; ky < 3; ++ky) {
            int ih = 2 * oh + ky - 1;
            if (ih < 0 || ih >= 64) continue;
            for (int kx = 0; kx < 3; ++kx) {
                int iw = 2 * ow + kx - 1;
                if (iw < 0 || iw >= 64) continue;
                s += xc[ih * 64 + iw] * wc[ky * 3 + kx];
            }
        }
    }
    a[gid] = f2bf(s);
}

// ---------------- naive e1: y2'[b,h,w,c] = down(x2)[c]*exp(2tanh(0.2*a1[c])) + a1[192+c] ----------------
__global__ __launch_bounds__(256)
void n_e1(const u16* __restrict__ a, const float* __restrict__ x,
          u16* __restrict__ y2)
{
    int gid = blockIdx.x * 256 + threadIdx.x;        // 6,291,456 exact
    int c = gid % 192;
    int pix = gid / 192;
    int b = pix >> 10, h = (pix >> 5) & 31, w = pix & 31;
    float a_s = bf2f(a[(size_t)pix * 384 + c]);
    float a_o = bf2f(a[(size_t)pix * 384 + 192 + c]);
    float xv = x[(((size_t)b * 96 + 48 + (c >> 2)) * 64 + (2 * h + ((c >> 1) & 1))) * 64
                 + (2 * w + (c & 1))];
    float e = expf(0.4f * a_s);            // exp(2*0.2*a)
    float sj = 2.f - 4.f / (e + 1.f);      // 2*tanh(0.2*a)
    y2[gid] = f2bf(xv * expf(sj) + a_o);
}

// ---------------- naive out, y2 half: out[b,o,h,w] (f32) for fwd[o]>=192 ----------------
__global__ __launch_bounds__(256)
void n_o2(const u16* __restrict__ y2, const float* __restrict__ scale,
          const float* __restrict__ offs, const int* __restrict__ fwd,
          float* __restrict__ out)
{
    int gid = blockIdx.x * 256 + threadIdx.x;        // 12,582,912 exact
    int w = gid & 31;
    int h = (gid >> 5) & 31;
    int t = gid >> 10;
    int o = t % 384;
    int b = t / 384;
    int c = fwd[o];
    if (c >= 192) {
        float z = bf2f(y2[(((size_t)b * 32 + h) * 32 + w) * 192 + (c - 192)]);
        out[gid] = z * scale[c] + offs[c];
    }
}

// ---------------- naive conv_lo: a2[b,oh,ow,n] = conv(y2', w_lo, stride1, pad1) ----------------
__global__ __launch_bounds__(256)
void n_conv_lo(const u16* __restrict__ y2, const float* __restrict__ w_lo,
               const float* __restrict__ b_lo, u16* __restrict__ a)
{
    int gid = blockIdx.x * 256 + threadIdx.x;        // 12,582,912 exact
    int n = gid % 384;
    int pix = gid / 384;
    int b = pix >> 10, oh = (pix >> 5) & 31, ow = pix & 31;
    float s = b_lo[n];
    for (int c = 0; c < 192; ++c) {
        const u16* yc = y2 + (size_t)b * (32 * 32 * 192) + c;
        const float* wc = w_lo + ((size_t)n * 192 + c) * 9;
        for (int ky = 0; ky < 3; ++ky) {
            int ih = oh + ky - 1;
            if (ih < 0 || ih >= 32) continue;
            for (int kx = 0; kx < 3; ++kx) {
                int iw = ow + kx - 1;
                if (iw < 0 || iw >= 32) continue;
                s += bf2f(yc[(ih * 32 + iw) * 192]) * wc[ky * 3 + kx];
            }
        }
    }
    a[gid] = f2bf(s);
}

// ---------------- naive out, y1 half: out[b,o,h,w] (f32) for fwd[o]<192 ----------------
// y1' = down(x1)[c]*exp(2tanh(0.2*a2[c])) + a2[192+c]
__global__ __launch_bounds__(256)
void n_o1(const float* __restrict__ x, const u16* __restrict__ a,
          const float* __restrict__ scale, const float* __restrict__ offs,
          const int* __restrict__ fwd, float* __restrict__ out)
{
    int gid = blockIdx.x * 256 + threadIdx.x;        // 12,582,912 exact
    int w = gid & 31;
    int h = (gid >> 5) & 31;
    int t = gid >> 10;
    int o = t % 384;
    int b = t / 384;
    int c = fwd[o];
    if (c < 192) {
        size_t pix = ((size_t)b * 32 + h) * 32 + w;
        float a_s = bf2f(a[pix * 384 + c]);
        float a_o = bf2f(a[pix * 384 + 192 + c]);
        float xv = x[(((size_t)b * 96 + (c >> 2)) * 64 + (2 * h + ((c >> 1) & 1))) * 64
                     + (2 * w + (c & 1))];
        float e = expf(0.4f * a_s);
        float sj = 2.f - 4.f / (e + 1.f);
        float z = xv * expf(sj) + a_o;
        out[gid] = z * scale[c] + offs[c];
    }
}

extern "C" void kernel_launch(void* const* d_in, const int* in_sizes, int n_in,
                              void* d_out, int out_size, void* d_ws, size_t ws_size,
                              hipStream_t stream)
{
    const float* x        = (const float*)d_in[0];
    const float* w_hi     = (const float*)d_in[1];
    const float* b_hi     = (const float*)d_in[2];
    const float* w_lo     = (const float*)d_in[3];
    const float* b_lo     = (const float*)d_in[4];
    const float* act_norm = (const float*)d_in[5];
    const float* act_off  = (const float*)d_in[6];
    const float* perm_w   = (const float*)d_in[7];
    float* out = (float*)d_out;             // OUTPUT is f32 (per reference)
    char* ws = (char*)d_ws;

    int*   fwd   = (int*)(ws + WS_FWD);
    float* scale = (float*)(ws + WS_SCALE);
    float* offs  = (float*)(ws + WS_OFFS);
    u16*   y2    = (u16*)(ws + WS_Y2);
    u16*   abuf  = (u16*)(ws + WS_A);       // a1, then a2

    k_prep0<<<2, 256, 0, stream>>>(perm_w, act_norm, act_off, fwd, scale, offs);
    n_conv_hi<<<49152, 256, 0, stream>>>(x, w_hi, b_hi, abuf);       // a1
    n_e1<<<24576, 256, 0, stream>>>(abuf, x, y2);                    // y2'
    n_o2<<<49152, 256, 0, stream>>>(y2, scale, offs, fwd, out);      // y2 half of out
    n_conv_lo<<<49152, 256, 0, stream>>>(y2, w_lo, b_lo, abuf);      // a2
    n_o1<<<49152, 256, 0, stream>>>(x, abuf, scale, offs, fwd, out); // y1 half of out
}

// Round 13
// 1220.942 us; speedup vs baseline: 73.8382x; 73.8382x over previous
//
#include <hip/hip_runtime.h>
#include <hip/hip_bf16.h>

typedef __attribute__((ext_vector_type(8))) short s16x8;
typedef __attribute__((ext_vector_type(4))) float f32x4;
typedef unsigned short u16;

// ---------------- workspace layout (bytes), total <= 41,943,040 (proven) ----------------
#define WS_FWD    0            // 384 int
#define WS_SCALE  4096         // 384 f32
#define WS_OFFS   6144         // 384 f32
#define WS_XD     2097152      // xd (b,h,w,192) bf16 = 12,582,912 B; later reused as y2'
#define WS_A      16777216     // a1/a2 bf16 (pix,384) = 25,165,824 B -> ends 41,943,040

static __device__ __forceinline__ u16 f2bf(float f) {
    __hip_bfloat16 h = __float2bfloat16(f);
    return *reinterpret_cast<u16*>(&h);
}
static __device__ __forceinline__ float bf2f(u16 u) {
    __hip_bfloat16 h = *reinterpret_cast<__hip_bfloat16*>(&u);
    return __bfloat162float(h);
}

// ---------------- prep: perm index + scale/offset (R9-proven) ----------------
__global__ __launch_bounds__(256)
void k_prep0(const float* __restrict__ pw, const float* __restrict__ an,
             const float* __restrict__ ao, int* __restrict__ fwd,
             float* __restrict__ scale, float* __restrict__ offs)
{
    int o = blockIdx.x * 256 + threadIdx.x;
    if (o >= 384) return;
    int f = 0;
    for (int c = 0; c < 384; ++c)
        if (pw[(size_t)o * 384 + c] > 0.5f) f = c;
    fwd[o]   = f;
    scale[o] = 0.2f * log1pf(expf(0.5f * an[o]));
    offs[o]  = ao[o];
}

// ---------------- X1d: down(x1) to (b,h,w,192) bf16 ----------------
__global__ __launch_bounds__(256)
void k_xd(const float* __restrict__ x, u16* __restrict__ xd)
{
    int gid = blockIdx.x * 256 + threadIdx.x;   // 6,291,456 exact
    int pix = gid / 192;
    int c = gid - pix * 192;                    // c = cin*4 + dy*2 + dx
    int b = pix >> 10, h = (pix >> 5) & 31, w = pix & 31;
    xd[gid] = f2bf(x[(((size_t)b * 96 + (c >> 2)) * 64 + (2 * h + ((c >> 1) & 1))) * 64
                     + (2 * w + (c & 1))]);
}

// ---------------- SIMPLE MFMA gemm: no LDS, no packed weights ----------------
// A: global vector loads from in_t (.,192) bf16; B: per-lane gather from RAW f32 weights.
// T=4: wraw = w_hi (384,48,3,3), down-domain tap formula inline.
// T=9: wraw = w_lo (384,192,3,3), w[n][c][t].
// Tile: M=64 (rows h0,h0+1), N=384 wave-split (96/wave). Same epilogue beliefs as R10.
template <int T>
__global__ __launch_bounds__(256)
void s_gemm(const u16* __restrict__ in_t, const float* __restrict__ wraw,
            const float* __restrict__ bias, u16* __restrict__ out_a)
{
    const int tid = threadIdx.x;
    const int lane = tid & 63;
    const int wave = tid >> 6;
    const int l16 = lane & 15;
    const int quad = lane >> 4;
    const int mblk = blockIdx.x;           // 512 blocks
    const int b = mblk >> 4;
    const int h0 = (mblk & 15) << 1;
    const int n0 = wave * 96;

    const f32x4 zero4 = {0.f, 0.f, 0.f, 0.f};
    f32x4 acc[4][6];
#pragma unroll
    for (int a = 0; a < 4; ++a)
#pragma unroll
        for (int c = 0; c < 6; ++c) acc[a][c] = zero4;

    for (int t = 0; t < T; ++t) {
        const int dh = (T == 4) ? ((t >> 1) - 1) : (t / 3 - 1);
        const int dw = (T == 4) ? ((t & 1) - 1) : (t % 3 - 1);
        for (int kc = 0; kc < 6; ++kc) {
            // ---- B fragments: gather from raw f32 weights ----
            s16x8 bf[6];
#pragma unroll
            for (int ns = 0; ns < 6; ++ns) {
                int n = n0 + ns * 16 + l16;
                s16x8 v;
#pragma unroll
                for (int j = 0; j < 8; ++j) {
                    int c = kc * 32 + quad * 8 + j;
                    float wv = 0.f;
                    if (T == 4) {
                        int th = t >> 1, tw = t & 1;
                        int cin = c >> 2, dy = (c >> 1) & 1, dx = c & 1;
                        if (!(th == 0 && dy == 0) && !(tw == 0 && dx == 0)) {
                            int ky = (th == 0) ? 0 : 1 + dy;
                            int kx = (tw == 0) ? 0 : 1 + dx;
                            wv = wraw[(((size_t)n * 48 + cin) * 3 + ky) * 3 + kx];
                        }
                    } else {
                        wv = wraw[((size_t)n * 192 + c) * 9 + t];
                    }
                    v[j] = (short)f2bf(wv);
                }
                bf[ns] = v;
            }
            // ---- A fragments: direct global vector loads, per-lane bounds check ----
            s16x8 af[4];
#pragma unroll
            for (int ms = 0; ms < 4; ++ms) {
                int m = ms * 16 + l16;
                int ih = h0 + (m >> 5) + dh;
                int iw = (m & 31) + dw;
                s16x8 v = {0, 0, 0, 0, 0, 0, 0, 0};
                if (ih >= 0 && ih < 32 && iw >= 0 && iw < 32)
                    v = *(const s16x8*)(in_t + (((size_t)b * 32 + ih) * 32 + iw) * 192
                                        + kc * 32 + quad * 8);
                af[ms] = v;
            }
            // ---- MFMA ----
#pragma unroll
            for (int ms = 0; ms < 4; ++ms)
#pragma unroll
                for (int ns = 0; ns < 6; ++ns)
                    acc[ms][ns] = __builtin_amdgcn_mfma_f32_16x16x32_bf16(
                        af[ms], bf[ns], acc[ms][ns], 0, 0, 0);
        }
    }

    // epilogue: C/D belief col(N)=lane&15, row(M)=quad*4+reg
#pragma unroll
    for (int ms = 0; ms < 4; ++ms) {
#pragma unroll
        for (int ns = 0; ns < 6; ++ns) {
            int n = n0 + ns * 16 + l16;
            float bv = bias[n];
#pragma unroll
            for (int r4 = 0; r4 < 4; ++r4) {
                int m = ms * 16 + quad * 4 + r4;
                int h = h0 + (m >> 5);
                int w = m & 31;
                out_a[(((size_t)b * 32 + h) * 32 + w) * 384 + n] =
                    f2bf(acc[ms][ns][r4] + bv);
            }
        }
    }
}

// ---------------- naive e1 (R9-proven) ----------------
__global__ __launch_bounds__(256)
void n_e1(const u16* __restrict__ a, const float* __restrict__ x,
          u16* __restrict__ y2)
{
    int gid = blockIdx.x * 256 + threadIdx.x;        // 6,291,456 exact
    int c = gid % 192;
    int pix = gid / 192;
    int b = pix >> 10, h = (pix >> 5) & 31, w = pix & 31;
    float a_s = bf2f(a[(size_t)pix * 384 + c]);
    float a_o = bf2f(a[(size_t)pix * 384 + 192 + c]);
    float xv = x[(((size_t)b * 96 + 48 + (c >> 2)) * 64 + (2 * h + ((c >> 1) & 1))) * 64
                 + (2 * w + (c & 1))];
    float e = expf(0.4f * a_s);
    float sj = 2.f - 4.f / (e + 1.f);
    y2[gid] = f2bf(xv * expf(sj) + a_o);
}

// ---------------- naive out y2-half (R9-proven) ----------------
__global__ __launch_bounds__(256)
void n_o2(const u16* __restrict__ y2, const float* __restrict__ scale,
          const float* __restrict__ offs, const int* __restrict__ fwd,
          float* __restrict__ out)
{
    int gid = blockIdx.x * 256 + threadIdx.x;        // 12,582,912 exact
    int w = gid & 31;
    int h = (gid >> 5) & 31;
    int t = gid >> 10;
    int o = t % 384;
    int b = t / 384;
    int c = fwd[o];
    if (c >= 192) {
        float z = bf2f(y2[(((size_t)b * 32 + h) * 32 + w) * 192 + (c - 192)]);
        out[gid] = z * scale[c] + offs[c];
    }
}

// ---------------- naive out y1-half (R9-proven) ----------------
__global__ __launch_bounds__(256)
void n_o1(const float* __restrict__ x, const u16* __restrict__ a,
          const float* __restrict__ scale, const float* __restrict__ offs,
          const int* __restrict__ fwd, float* __restrict__ out)
{
    int gid = blockIdx.x * 256 + threadIdx.x;        // 12,582,912 exact
    int w = gid & 31;
    int h = (gid >> 5) & 31;
    int t = gid >> 10;
    int o = t % 384;
    int b = t / 384;
    int c = fwd[o];
    if (c < 192) {
        size_t pix = ((size_t)b * 32 + h) * 32 + w;
        float a_s = bf2f(a[pix * 384 + c]);
        float a_o = bf2f(a[pix * 384 + 192 + c]);
        float xv = x[(((size_t)b * 96 + (c >> 2)) * 64 + (2 * h + ((c >> 1) & 1))) * 64
                     + (2 * w + (c & 1))];
        float e = expf(0.4f * a_s);
        float sj = 2.f - 4.f / (e + 1.f);
        float z = xv * expf(sj) + a_o;
        out[gid] = z * scale[c] + offs[c];
    }
}

extern "C" void kernel_launch(void* const* d_in, const int* in_sizes, int n_in,
                              void* d_out, int out_size, void* d_ws, size_t ws_size,
                              hipStream_t stream)
{
    const float* x        = (const float*)d_in[0];
    const float* w_hi     = (const float*)d_in[1];
    const float* b_hi     = (const float*)d_in[2];
    const float* w_lo     = (const float*)d_in[3];
    const float* b_lo     = (const float*)d_in[4];
    const float* act_norm = (const float*)d_in[5];
    const float* act_off  = (const float*)d_in[6];
    const float* perm_w   = (const float*)d_in[7];
    float* out = (float*)d_out;
    char* ws = (char*)d_ws;

    int*   fwd   = (int*)(ws + WS_FWD);
    float* scale = (float*)(ws + WS_SCALE);
    float* offs  = (float*)(ws + WS_OFFS);
    u16*   xd    = (u16*)(ws + WS_XD);   // xd, then reused as y2'
    u16*   abuf  = (u16*)(ws + WS_A);    // a1, then a2

    k_prep0<<<2, 256, 0, stream>>>(perm_w, act_norm, act_off, fwd, scale, offs);
    k_xd<<<24576, 256, 0, stream>>>(x, xd);
    s_gemm<4><<<512, 256, 0, stream>>>(xd, w_hi, b_hi, abuf);        // a1 (MFMA, no LDS/packs)
    n_e1<<<24576, 256, 0, stream>>>(abuf, x, xd);                    // y2' (over xd)
    n_o2<<<49152, 256, 0, stream>>>(xd, scale, offs, fwd, out);      // y2 half of out
    s_gemm<9><<<512, 256, 0, stream>>>(xd, w_lo, b_lo, abuf);        // a2 (MFMA, no LDS/packs)
    n_o1<<<49152, 256, 0, stream>>>(x, abuf, scale, offs, fwd, out); // y1 half of out
}